// Round 13
// baseline (724.700 us; speedup 1.0000x reference)
//
#include <hip/hip_runtime.h>
#include <math.h>

#define Nn 16384
#define Fd 64
#define Hd 128
#define Kk 32

typedef short bfrag __attribute__((ext_vector_type(8)));    // 8 bf16 = 4 VGPR
typedef float f32x16 __attribute__((ext_vector_type(16)));  // MFMA 32x32 acc

#define FMA16(acc, qv, pv) \
  acc[0][0]=fmaf(qv.x,pv.x,acc[0][0]); acc[0][1]=fmaf(qv.x,pv.y,acc[0][1]); \
  acc[0][2]=fmaf(qv.x,pv.z,acc[0][2]); acc[0][3]=fmaf(qv.x,pv.w,acc[0][3]); \
  acc[1][0]=fmaf(qv.y,pv.x,acc[1][0]); acc[1][1]=fmaf(qv.y,pv.y,acc[1][1]); \
  acc[1][2]=fmaf(qv.y,pv.z,acc[1][2]); acc[1][3]=fmaf(qv.y,pv.w,acc[1][3]); \
  acc[2][0]=fmaf(qv.z,pv.x,acc[2][0]); acc[2][1]=fmaf(qv.z,pv.y,acc[2][1]); \
  acc[2][2]=fmaf(qv.z,pv.z,acc[2][2]); acc[2][3]=fmaf(qv.z,pv.w,acc[2][3]); \
  acc[3][0]=fmaf(qv.w,pv.x,acc[3][0]); acc[3][1]=fmaf(qv.w,pv.y,acc[3][1]); \
  acc[3][2]=fmaf(qv.w,pv.z,acc[3][2]); acc[3][3]=fmaf(qv.w,pv.w,acc[3][3]);

// ---------------- hidden0 = x @ W_in + b_in ; sq[i] = sum(x_i^2) ----------------
__global__ __launch_bounds__(256) void k_input(const float* __restrict__ x,
    const float* __restrict__ W, const float* __restrict__ b,
    float* __restrict__ hid, float* __restrict__ sq) {
  const int t = threadIdx.x;
  const int i = (blockIdx.x << 1) + (t >> 7);
  const int h = t & 127;
  const float* xr = x + (size_t)i * Fd;
  float acc = 0.f, s = 0.f;
#pragma unroll 8
  for (int f = 0; f < Fd; ++f) {
    float xv = xr[f];
    acc = fmaf(xv, W[f * Hd + h], acc);
    s = fmaf(xv, xv, s);
  }
  hid[(size_t)i * Hd + h] = acc + b[h];
  if (h == 0) sq[i] = s;
}

// ------------- precompute x as bf16 hi/lo in MFMA-fragment order -------------
__global__ __launch_bounds__(256) void k_prep(const float* __restrict__ x,
    short* __restrict__ xh, short* __restrict__ xl) {
  const int gid = blockIdx.x * 256 + threadIdx.x;
  const int p = gid >> 3, sub = gid & 7;
  const float* src = x + (size_t)p * Fd + sub * 8;
  float4 v0 = *(const float4*)src;
  float4 v1 = *(const float4*)(src + 4);
  float vv[8] = {v0.x, v0.y, v0.z, v0.w, v1.x, v1.y, v1.z, v1.w};
  bfrag hi, lo;
#pragma unroll
  for (int j = 0; j < 8; ++j) {
    unsigned u = __float_as_uint(vv[j]);
    unsigned r = u + 0x7fffu + ((u >> 16) & 1u);
    unsigned short hb = (unsigned short)(r >> 16);
    float hf = __uint_as_float((unsigned)hb << 16);
    float lof = vv[j] - hf;
    unsigned ul = __float_as_uint(lof);
    unsigned rl = ul + 0x7fffu + ((ul >> 16) & 1u);
    hi[j] = (short)hb;
    lo[j] = (short)(rl >> 16);
  }
  const size_t o = (size_t)(p >> 5) * 2048 + (size_t)sub * 256 + (size_t)(p & 31) * 8;
  *(bfrag*)(xh + o) = hi;
  *(bfrag*)(xl + o) = lo;
}

// ---------------- KNN pass 1: split-K, per-lane SORTED REGISTER top-32 ----------------
// Grid 1024: (qblk = bid>>1, half = bid&1), 64 tiles of 128 pts each.
// mfma(A=points, B=queries): lane (q=lane&31, h=lane>>5) holds 16 pt-dists of ITS
// query in regs. Top-32 = sorted ascending 32-register list kl[]; insert =
// kl[i]=min(max(key,kl[i-1]),kl[i]) descending (63 predication-free VALU ops),
// gated per static row by __any(key < kl[31]). No LDS in hot loop. Result is a
// pure function of the key multiset -> fully deterministic.
#define LSTR 33

__global__ __launch_bounds__(256, 3) void k_knn(const short* __restrict__ xbhi,
    const short* __restrict__ xblo, const float* __restrict__ sq,
    unsigned* __restrict__ part) {
  __shared__ unsigned tk[256 * LSTR];   // final-merge staging only (33.8 KB)
  __shared__ unsigned ms[512];          // merge scratch (2 KB)

  const int t = threadIdx.x;
  const int w = t >> 6;
  const int lane = t & 63;
  const int h = lane >> 5;
  const int q = lane & 31;
  const int qblk = (int)(blockIdx.x >> 1);
  const int half = (int)(blockIdx.x & 1);
  const int qg0 = qblk * 32;
  const int t0 = half * 64;
  const int selfq = qg0 + q;
  const float sqq = sq[selfq];
  const int selfTl = qg0 >> 7;            // wave-uniform
  const int selfW = (qg0 >> 5) & 3;       // wave-uniform
  const int selfH = (q >> 2) & 1;
  const int selfR = (q & 3) + 4 * (q >> 3);

  const char* xh = (const char*)xbhi;
  const char* xl = (const char*)xblo;

  bfrag qhi[4], qlo[4];
  {
    const size_t a0 = (size_t)qblk * 4096 + (size_t)lane * 16;
#pragma unroll
    for (int s = 0; s < 4; ++s) {
      qhi[s] = *(const bfrag*)(xh + a0 + s * 1024);
      qlo[s] = *(const bfrag*)(xl + a0 + s * 1024);
    }
  }
  asm volatile("" :: "v"(qhi[0]), "v"(qhi[1]), "v"(qhi[2]), "v"(qhi[3]),
                     "v"(qlo[0]), "v"(qlo[1]), "v"(qlo[2]), "v"(qlo[3]));

  unsigned kl[32];
#pragma unroll
  for (int e = 0; e < 32; ++e) kl[e] = 0xFFFFFFFFu;

#define LOADP(GT, PH, PL) { \
  const size_t bb_ = (size_t)((GT) * 4 + w) * 4096 + (size_t)lane * 16; \
  _Pragma("unroll") for (int s_ = 0; s_ < 4; ++s_) { \
    PH[s_] = *(const bfrag*)(xh + bb_ + s_ * 1024); \
    PL[s_] = *(const bfrag*)(xl + bb_ + s_ * 1024); } }

#define PIN(PH, PL) asm volatile("" :: "v"(PH[0]), "v"(PH[1]), "v"(PH[2]), "v"(PH[3]), \
                                       "v"(PL[0]), "v"(PL[1]), "v"(PL[2]), "v"(PL[3]));

#define MFMA12(A0, PH, PL) { \
  _Pragma("unroll") for (int s_ = 0; s_ < 4; ++s_) \
    A0 = __builtin_amdgcn_mfma_f32_32x32x16_bf16(PH[s_], qhi[s_], A0, 0, 0, 0); \
  _Pragma("unroll") for (int s_ = 0; s_ < 4; ++s_) \
    A0 = __builtin_amdgcn_mfma_f32_32x32x16_bf16(PH[s_], qlo[s_], A0, 0, 0, 0); \
  _Pragma("unroll") for (int s_ = 0; s_ < 4; ++s_) \
    A0 = __builtin_amdgcn_mfma_f32_32x32x16_bf16(PL[s_], qhi[s_], A0, 0, 0, 0); }

  // branchless sorted insert (drop max): kl stays sorted ascending
#define INSKEY(KEY) { \
  _Pragma("unroll") for (int i_ = 31; i_ >= 1; --i_) { \
    const unsigned a_ = (KEY) > kl[i_ - 1] ? (KEY) : kl[i_ - 1]; \
    kl[i_] = a_ < kl[i_] ? a_ : kl[i_]; } \
  kl[0] = (KEY) < kl[0] ? (KEY) : kl[0]; }

#define STEP(LT, PHc, PLc, PHn, PLn) { \
  const int gT_ = t0 + (LT); \
  if ((LT) + 1 < 64) LOADP(gT_ + 1, PHn, PLn) \
  f32x16 a0_; \
  _Pragma("unroll") for (int i_ = 0; i_ < 16; ++i_) a0_[i_] = 0.f; \
  MFMA12(a0_, PHc, PLc) \
  PIN(PHn, PLn) \
  const float* sb_ = sq + gT_ * 128 + w * 32 + 4 * h; \
  const bool selfHere_ = (gT_ == selfTl) && (w == selfW); \
  const int pb_ = gT_ * 128 + w * 32 + 4 * h; \
  _Pragma("unroll") for (int g_ = 0; g_ < 4; ++g_) { \
    const float4 sv_ = *(const float4*)(sb_ + g_ * 8); \
    const float sg_[4] = {sv_.x, sv_.y, sv_.z, sv_.w}; \
    _Pragma("unroll") for (int u_ = 0; u_ < 4; ++u_) { \
      const int r_ = g_ * 4 + u_; \
      float d2_ = fmaf(-2.0f, a0_[r_], sqq + sg_[u_]); \
      if (selfHere_ && h == selfH && r_ == selfR) d2_ = 1e30f; \
      unsigned dq_ = (unsigned)(d2_ * 256.0f); \
      dq_ = dq_ > 0x3FFEFu ? 0x3FFEFu : dq_; \
      const unsigned key_ = (dq_ << 14) | (unsigned)(pb_ + r_ + (r_ & ~3)); \
      if (__any(key_ < kl[31])) INSKEY(key_) \
    } } }

  bfrag phA[4], plA[4], phB[4], plB[4];
  LOADP(t0, phA, plA) PIN(phA, plA)
  for (int lt = 0; lt < 62; lt += 2) {
    STEP(lt, phA, plA, phB, plB)
    STEP(lt + 1, phB, plB, phA, plA)
  }
  STEP(62, phA, plA, phB, plB)
  STEP(63, phB, plB, phA, plA)

  // dump sorted register lists to LDS for the in-block merge
#pragma unroll
  for (int e = 0; e < 32; ++e) tk[t * LSTR + e] = kl[e];
  __syncthreads();

  // ---- in-block merge: 8 lane-lists -> sorted top-32/query -> part ----
#define SORT64(V) { \
  _Pragma("unroll") for (int k_ = 2; k_ <= 64; k_ <<= 1) { \
    _Pragma("unroll") for (int j_ = k_ >> 1; j_ >= 1; j_ >>= 1) { \
      const unsigned o_ = (unsigned)__shfl_xor((int)V, j_); \
      const bool km_ = ((lane & j_) == 0) == ((lane & k_) == 0); \
      V = km_ ? (V < o_ ? V : o_) : (V > o_ ? V : o_); \
    } } }

#define MERGE6(V) { \
  _Pragma("unroll") for (int j_ = 32; j_ >= 1; j_ >>= 1) { \
    const unsigned o_ = (unsigned)__shfl_xor((int)V, j_); \
    const bool km_ = ((lane & j_) == 0); \
    V = km_ ? (V < o_ ? V : o_) : (V > o_ ? V : o_); \
  } }

  unsigned* S = &ms[w * 128];
  for (int s8 = 0; s8 < 8; ++s8) {
    const int qq = w * 8 + s8;
#pragma unroll
    for (int w2 = 0; w2 < 4; ++w2) {
      unsigned v = tk[(w2 * 64 + (lane & 32) + qq) * LSTR + (lane & 31)];
      SORT64(v)
      if (lane < 32) S[w2 * 32 + lane] = v;
    }
    {
      unsigned v = (lane < 32) ? S[0 * 32 + lane] : S[1 * 32 + (63 - lane)];
      MERGE6(v)
      if (lane < 32) S[0 * 32 + lane] = v;
    }
    {
      unsigned v = (lane < 32) ? S[2 * 32 + lane] : S[3 * 32 + (63 - lane)];
      MERGE6(v)
      if (lane < 32) S[2 * 32 + lane] = v;
    }
    {
      unsigned v = (lane < 32) ? S[0 * 32 + lane] : S[2 * 32 + (63 - lane)];
      MERGE6(v)
      if (lane < 32)
        part[(size_t)(qg0 + qq) * 64 + half * 32 + lane] = v;
    }
  }
#undef LOADP
#undef PIN
#undef MFMA12
#undef INSKEY
#undef STEP
#undef SORT64
#undef MERGE6
}

// ---------------- KNN pass 2: merge two sorted-32 lists + softmax ----------------
__global__ __launch_bounds__(256) void k_merge(const unsigned* __restrict__ part,
    unsigned short* __restrict__ nidx, float* __restrict__ nw) {
  const int t = threadIdx.x;
  const int w = t >> 6;
  const int lane = t & 63;
  const int q = (int)blockIdx.x * 4 + w;
  const int src = (lane < 32) ? lane : (95 - lane);
  unsigned v = part[(size_t)q * 64 + src];
#pragma unroll
  for (int j = 32; j >= 1; j >>= 1) {
    const unsigned o = (unsigned)__shfl_xor((int)v, j);
    const bool mn = ((lane & j) == 0);
    v = mn ? (v < o ? v : o) : (v > o ? v : o);
  }
  const float d = sqrtf((float)(v >> 14) * (1.0f / 256.0f));
  const float dmin = __shfl(d, 0);
  float e = (lane < 32) ? __expf((dmin - d) * 2.0f) : 0.f;
  float s2 = e;
#pragma unroll
  for (int m = 1; m < 64; m <<= 1) s2 += __shfl_xor(s2, m);
  if (lane < 32) {
    nw[(size_t)q * Kk + lane] = e / s2;
    nidx[(size_t)q * Kk + lane] = (unsigned short)(v & 0x3FFFu);
  }
}

// ---------------- one message-pass step, fused: gather+MLP+LN ----------------
#define RB 32
#define US 36

__global__ __launch_bounds__(256) void k_step(const float* __restrict__ x,
    const float* __restrict__ hin, const unsigned short* __restrict__ nidx,
    const float* __restrict__ nw, const float* __restrict__ Wm1,
    const float* __restrict__ bm1, const float* __restrict__ Wm2,
    const float* __restrict__ bm2, const float* __restrict__ g,
    const float* __restrict__ be, float* __restrict__ hout) {
  __shared__ float updT[2 * Hd + Fd][US];  // upd_in transposed: 320 x 36 (46 KB)
  __shared__ float t1T[Hd][US];            // silu(GEMM1) transposed (18 KB)
  const int t = threadIdx.x;
  const int r0 = blockIdx.x * RB;

  { // stage: hidden | agg (gather) | x, all transposed
    const int r = t >> 3, s = t & 7;
    const int i = r0 + r;
    const float* hr = hin + (size_t)i * Hd + (s << 4);
#pragma unroll
    for (int u = 0; u < 4; ++u) {
      float4 v = *(const float4*)(hr + (u << 2));
      const int c = (s << 4) + (u << 2);
      updT[c + 0][r] = v.x; updT[c + 1][r] = v.y;
      updT[c + 2][r] = v.z; updT[c + 3][r] = v.w;
    }
    float a[16];
#pragma unroll
    for (int u = 0; u < 16; ++u) a[u] = 0.f;
    const unsigned short* ir = nidx + i * Kk;
    const float* wr = nw + i * Kk;
    for (int k = 0; k < Kk; ++k) {
      const float wk = wr[k];
      const float* hv = hin + (size_t)ir[k] * Hd + (s << 4);
#pragma unroll
      for (int u = 0; u < 4; ++u) {
        float4 v = *(const float4*)(hv + (u << 2));
        a[(u << 2) + 0] = fmaf(wk, v.x, a[(u << 2) + 0]);
        a[(u << 2) + 1] = fmaf(wk, v.y, a[(u << 2) + 1]);
        a[(u << 2) + 2] = fmaf(wk, v.z, a[(u << 2) + 2]);
        a[(u << 2) + 3] = fmaf(wk, v.w, a[(u << 2) + 3]);
      }
    }
#pragma unroll
    for (int u = 0; u < 16; ++u) updT[Hd + (s << 4) + u][r] = a[u];
    const float* xr = x + (size_t)i * Fd + (s << 3);
    float4 x0 = *(const float4*)(xr);
    float4 x1 = *(const float4*)(xr + 4);
    const int c = 2 * Hd + (s << 3);
    updT[c + 0][r] = x0.x; updT[c + 1][r] = x0.y;
    updT[c + 2][r] = x0.z; updT[c + 3][r] = x0.w;
    updT[c + 4][r] = x1.x; updT[c + 5][r] = x1.y;
    updT[c + 6][r] = x1.z; updT[c + 7][r] = x1.w;
  }
  __syncthreads();

  const int rg = t >> 5, cg = t & 31;
  const int rr = rg << 2, cc = cg << 2;
  { // GEMM1 [32x320]x[320x128] + silu -> t1T
    float acc[4][4] = {};
#pragma unroll 4
    for (int k = 0; k < 2 * Hd + Fd; ++k) {
      float4 uv = *(const float4*)&updT[k][rr];
      float4 wv = *(const float4*)&Wm1[k * Hd + cc];
      FMA16(acc, uv, wv)
    }
    float4 b1 = *(const float4*)&bm1[cc];
    float bb1[4] = {b1.x, b1.y, b1.z, b1.w};
#pragma unroll
    for (int a = 0; a < 4; ++a)
#pragma unroll
      for (int b = 0; b < 4; ++b) {
        const float z = acc[a][b] + bb1[b];
        t1T[cc + b][rr + a] = z / (1.0f + __expf(-z));
      }
  }
  __syncthreads();
  { // GEMM2 [32x128]x[128x128] + residual + LayerNorm
    float acc[4][4] = {};
#pragma unroll 4
    for (int k = 0; k < Hd; ++k) {
      float4 uv = *(const float4*)&t1T[k][rr];
      float4 wv = *(const float4*)&Wm2[k * Hd + cc];
      FMA16(acc, uv, wv)
    }
    float4 b2 = *(const float4*)&bm2[cc];
    float bb2[4] = {b2.x, b2.y, b2.z, b2.w};
    float v[4][4];
#pragma unroll
    for (int b = 0; b < 4; ++b) {
      float4 hres = *(const float4*)&updT[cc + b][rr];  // residual = staged hidden
      v[0][b] = hres.x + acc[0][b] + bb2[b];
      v[1][b] = hres.y + acc[1][b] + bb2[b];
      v[2][b] = hres.z + acc[2][b] + bb2[b];
      v[3][b] = hres.w + acc[3][b] + bb2[b];
    }
    float4 gv = *(const float4*)&g[cc];
    float4 bev = *(const float4*)&be[cc];
    float gg[4] = {gv.x, gv.y, gv.z, gv.w};
    float eb[4] = {bev.x, bev.y, bev.z, bev.w};
#pragma unroll
    for (int a = 0; a < 4; ++a) {
      float sm = v[a][0] + v[a][1] + v[a][2] + v[a][3];
      float s2 = 0.f;
#pragma unroll
      for (int b = 0; b < 4; ++b) s2 = fmaf(v[a][b], v[a][b], s2);
#pragma unroll
      for (int m = 1; m < 32; m <<= 1) {
        sm += __shfl_xor(sm, m);
        s2 += __shfl_xor(s2, m);
      }
      const float mean = sm * (1.0f / 128.0f);
      const float var = fmaxf(s2 * (1.0f / 128.0f) - mean * mean, 0.0f);
      const float rstd = rsqrtf(var + 1e-5f);
      float4 o;
      o.x = (v[a][0] - mean) * rstd * gg[0] + eb[0];
      o.y = (v[a][1] - mean) * rstd * gg[1] + eb[1];
      o.z = (v[a][2] - mean) * rstd * gg[2] + eb[2];
      o.w = (v[a][3] - mean) * rstd * gg[3] + eb[3];
      *(float4*)&hout[(size_t)(r0 + rr + a) * Hd + cc] = o;
    }
  }
}

// ---------------- readout: softplus(silu([h,x]@Wr1+b)@Wr2+b) ----------------
__global__ __launch_bounds__(256) void k_out(const float* __restrict__ x,
    const float* __restrict__ hin, const float* __restrict__ Wr1,
    const float* __restrict__ br1, const float* __restrict__ Wr2,
    const float* __restrict__ br2, float* __restrict__ out) {
  __shared__ float rT[Hd + Fd][US];  // 192 x 36 (27 KB)
  const int t = threadIdx.x;
  const int r0 = blockIdx.x * RB;
  {
    const int r = t >> 3, s = t & 7;
    const int i = r0 + r;
    const float* hr = hin + (size_t)i * Hd + (s << 4);
#pragma unroll
    for (int u = 0; u < 4; ++u) {
      float4 v = *(const float4*)(hr + (u << 2));
      const int c = (s << 4) + (u << 2);
      rT[c + 0][r] = v.x; rT[c + 1][r] = v.y;
      rT[c + 2][r] = v.z; rT[c + 3][r] = v.w;
    }
    const float* xr = x + (size_t)i * Fd + (s << 3);
    float4 x0 = *(const float4*)(xr);
    float4 x1 = *(const float4*)(xr + 4);
    const int c = Hd + (s << 3);
    rT[c + 0][r] = x0.x; rT[c + 1][r] = x0.y;
    rT[c + 2][r] = x0.z; rT[c + 3][r] = x0.w;
    rT[c + 4][r] = x1.x; rT[c + 5][r] = x1.y;
    rT[c + 6][r] = x1.z; rT[c + 7][r] = x1.w;
  }
  __syncthreads();
  const int rg = t >> 5, cg = t & 31;
  const int rr = rg << 2, cc = cg << 2;
  float acc[4][4] = {};
#pragma unroll 4
  for (int k = 0; k < Hd + Fd; ++k) {
    float4 uv = *(const float4*)&rT[k][rr];
    float4 wv = *(const float4*)&Wr1[k * Hd + cc];
    FMA16(acc, uv, wv)
  }
  float4 b1 = *(const float4*)&br1[cc];
  float bb1[4] = {b1.x, b1.y, b1.z, b1.w};
  float4 w2 = *(const float4*)&Wr2[cc];
  float ww[4] = {w2.x, w2.y, w2.z, w2.w};
  float part[4];
#pragma unroll
  for (int a = 0; a < 4; ++a) {
    part[a] = 0.f;
#pragma unroll
    for (int b = 0; b < 4; ++b) {
      const float z = acc[a][b] + bb1[b];
      const float sil = z / (1.0f + __expf(-z));
      part[a] = fmaf(sil, ww[b], part[a]);
    }
  }
#pragma unroll
  for (int m = 1; m < 32; m <<= 1) {
#pragma unroll
    for (int a = 0; a < 4; ++a) part[a] += __shfl_xor(part[a], m);
  }
  if (cg == 0) {
    const float bias = br2[0];
#pragma unroll
    for (int a = 0; a < 4; ++a) {
      const float rv = part[a] + bias;
      out[r0 + rr + a] = fmaxf(rv, 0.0f) + log1pf(__expf(-fabsf(rv)));
    }
  }
}

extern "C" void kernel_launch(void* const* d_in, const int* in_sizes, int n_in,
                              void* d_out, int out_size, void* d_ws, size_t ws_size,
                              hipStream_t stream) {
  const float* x    = (const float*)d_in[0];
  const float* W_in = (const float*)d_in[1];
  const float* b_in = (const float*)d_in[2];
  const float* W_m1 = (const float*)d_in[3];
  const float* b_m1 = (const float*)d_in[4];
  const float* W_m2 = (const float*)d_in[5];
  const float* b_m2 = (const float*)d_in[6];
  const float* ln_g = (const float*)d_in[7];
  const float* ln_b = (const float*)d_in[8];
  const float* W_r1 = (const float*)d_in[9];
  const float* b_r1 = (const float*)d_in[10];
  const float* W_r2 = (const float*)d_in[11];
  const float* b_r2 = (const float*)d_in[12];
  float* out = (float*)d_out;

  char* ws = (char*)d_ws;
  const size_t MB = (size_t)1 << 20;
  float*          hidA = (float*)(ws);                 // 8 MB
  float*          hidB = (float*)(ws + 8 * MB);        // 8 MB (aliases partbuf)
  unsigned*       partb = (unsigned*)(ws + 8 * MB);    // 4 MB, dead before hidB use
  short*          xbhi = (short*)(ws + 16 * MB);       // 2 MB
  short*          xblo = (short*)(ws + 18 * MB);       // 2 MB
  unsigned short* nidx = (unsigned short*)(ws + 20 * MB);  // 1 MB
  float*          nw   = (float*)(ws + 21 * MB);       // 2 MB
  float*          sq   = (float*)(ws + 23 * MB);       // 64 KB

  k_input<<<dim3(Nn / 2), dim3(256), 0, stream>>>(x, W_in, b_in, hidA, sq);
  k_prep<<<dim3(Nn * 8 / 256), dim3(256), 0, stream>>>(x, xbhi, xblo);
  k_knn<<<dim3(Nn / 32 * 2), dim3(256), 0, stream>>>(xbhi, xblo, sq, partb);
  k_merge<<<dim3(Nn / 4), dim3(256), 0, stream>>>(partb, nidx, nw);
  k_step<<<dim3(Nn / RB), dim3(256), 0, stream>>>(x, hidA, nidx, nw, W_m1, b_m1,
                                                  W_m2, b_m2, ln_g, ln_b, hidB);
  k_step<<<dim3(Nn / RB), dim3(256), 0, stream>>>(x, hidB, nidx, nw, W_m1, b_m1,
                                                  W_m2, b_m2, ln_g, ln_b, hidA);
  k_out<<<dim3(Nn / RB), dim3(256), 0, stream>>>(x, hidA, W_r1, b_r1, W_r2, b_r2, out);
}

// Round 14
// 722.160 us; speedup vs baseline: 1.0035x; 1.0035x over previous
//
#include <hip/hip_runtime.h>
#include <math.h>

#define Nn 16384
#define Fd 64
#define Hd 128
#define Kk 32

typedef short bfrag __attribute__((ext_vector_type(8)));    // 8 bf16 = 4 VGPR
typedef float f32x16 __attribute__((ext_vector_type(16)));  // MFMA 32x32 acc

#define FMA16(acc, qv, pv) \
  acc[0][0]=fmaf(qv.x,pv.x,acc[0][0]); acc[0][1]=fmaf(qv.x,pv.y,acc[0][1]); \
  acc[0][2]=fmaf(qv.x,pv.z,acc[0][2]); acc[0][3]=fmaf(qv.x,pv.w,acc[0][3]); \
  acc[1][0]=fmaf(qv.y,pv.x,acc[1][0]); acc[1][1]=fmaf(qv.y,pv.y,acc[1][1]); \
  acc[1][2]=fmaf(qv.y,pv.z,acc[1][2]); acc[1][3]=fmaf(qv.y,pv.w,acc[1][3]); \
  acc[2][0]=fmaf(qv.z,pv.x,acc[2][0]); acc[2][1]=fmaf(qv.z,pv.y,acc[2][1]); \
  acc[2][2]=fmaf(qv.z,pv.z,acc[2][2]); acc[2][3]=fmaf(qv.z,pv.w,acc[2][3]); \
  acc[3][0]=fmaf(qv.w,pv.x,acc[3][0]); acc[3][1]=fmaf(qv.w,pv.y,acc[3][1]); \
  acc[3][2]=fmaf(qv.w,pv.z,acc[3][2]); acc[3][3]=fmaf(qv.w,pv.w,acc[3][3]);

// ---------------- hidden0 = x @ W_in + b_in ; sq[i] = sum(x_i^2) ----------------
__global__ __launch_bounds__(256) void k_input(const float* __restrict__ x,
    const float* __restrict__ W, const float* __restrict__ b,
    float* __restrict__ hid, float* __restrict__ sq) {
  const int t = threadIdx.x;
  const int i = (blockIdx.x << 1) + (t >> 7);
  const int h = t & 127;
  const float* xr = x + (size_t)i * Fd;
  float acc = 0.f, s = 0.f;
#pragma unroll 8
  for (int f = 0; f < Fd; ++f) {
    float xv = xr[f];
    acc = fmaf(xv, W[f * Hd + h], acc);
    s = fmaf(xv, xv, s);
  }
  hid[(size_t)i * Hd + h] = acc + b[h];
  if (h == 0) sq[i] = s;
}

// ------------- precompute x as bf16 hi/lo in MFMA-fragment order -------------
__global__ __launch_bounds__(256) void k_prep(const float* __restrict__ x,
    short* __restrict__ xh, short* __restrict__ xl) {
  const int gid = blockIdx.x * 256 + threadIdx.x;
  const int p = gid >> 3, sub = gid & 7;
  const float* src = x + (size_t)p * Fd + sub * 8;
  float4 v0 = *(const float4*)src;
  float4 v1 = *(const float4*)(src + 4);
  float vv[8] = {v0.x, v0.y, v0.z, v0.w, v1.x, v1.y, v1.z, v1.w};
  bfrag hi, lo;
#pragma unroll
  for (int j = 0; j < 8; ++j) {
    unsigned u = __float_as_uint(vv[j]);
    unsigned r = u + 0x7fffu + ((u >> 16) & 1u);
    unsigned short hb = (unsigned short)(r >> 16);
    float hf = __uint_as_float((unsigned)hb << 16);
    float lof = vv[j] - hf;
    unsigned ul = __float_as_uint(lof);
    unsigned rl = ul + 0x7fffu + ((ul >> 16) & 1u);
    hi[j] = (short)hb;
    lo[j] = (short)(rl >> 16);
  }
  const size_t o = (size_t)(p >> 5) * 2048 + (size_t)sub * 256 + (size_t)(p & 31) * 8;
  *(bfrag*)(xh + o) = hi;
  *(bfrag*)(xl + o) = lo;
}

// ---------------- KNN pass 1: split-K, NAMED-REGISTER sorted top-32 ----------------
// Grid 1024: (qblk = bid>>1, half = bid&1), 64 tiles of 128 pts each.
// mfma(A=points, B=queries): lane (q=lane&31, h=lane>>5) holds 16 pt-dists of ITS
// query in regs. Top-32 = 32 NAMED u32 registers K0..K31, sorted ascending;
// insert = Ki = min(max(key,K(i-1)), Ki) descending (63 flat VALU ops, exact,
// order-independent), gated per static row by __any(key < K31). Named scalars
// force register residency (r13's kl[32] array was demoted to scratch).
#define LSTR 33

__global__ __launch_bounds__(256, 2) void k_knn(const short* __restrict__ xbhi,
    const short* __restrict__ xblo, const float* __restrict__ sq,
    unsigned* __restrict__ part) {
  __shared__ unsigned tk[256 * LSTR];   // final-merge staging only (33.8 KB)
  __shared__ unsigned ms[512];          // merge scratch (2 KB)

  const int t = threadIdx.x;
  const int w = t >> 6;
  const int lane = t & 63;
  const int h = lane >> 5;
  const int q = lane & 31;
  const int qblk = (int)(blockIdx.x >> 1);
  const int half = (int)(blockIdx.x & 1);
  const int qg0 = qblk * 32;
  const int t0 = half * 64;
  const int selfq = qg0 + q;
  const float sqq = sq[selfq];
  const int selfTl = qg0 >> 7;            // wave-uniform
  const int selfW = (qg0 >> 5) & 3;       // wave-uniform
  const int selfH = (q >> 2) & 1;
  const int selfR = (q & 3) + 4 * (q >> 3);

  const char* xh = (const char*)xbhi;
  const char* xl = (const char*)xblo;

  bfrag qhi[4], qlo[4];
  {
    const size_t a0 = (size_t)qblk * 4096 + (size_t)lane * 16;
#pragma unroll
    for (int s = 0; s < 4; ++s) {
      qhi[s] = *(const bfrag*)(xh + a0 + s * 1024);
      qlo[s] = *(const bfrag*)(xl + a0 + s * 1024);
    }
  }
  asm volatile("" :: "v"(qhi[0]), "v"(qhi[1]), "v"(qhi[2]), "v"(qhi[3]),
                     "v"(qlo[0]), "v"(qlo[1]), "v"(qlo[2]), "v"(qlo[3]));

  // 32 NAMED registers, sorted ascending; init = +inf key
  unsigned K0=~0u,K1=~0u,K2=~0u,K3=~0u,K4=~0u,K5=~0u,K6=~0u,K7=~0u,
           K8=~0u,K9=~0u,K10=~0u,K11=~0u,K12=~0u,K13=~0u,K14=~0u,K15=~0u,
           K16=~0u,K17=~0u,K18=~0u,K19=~0u,K20=~0u,K21=~0u,K22=~0u,K23=~0u,
           K24=~0u,K25=~0u,K26=~0u,K27=~0u,K28=~0u,K29=~0u,K30=~0u,K31=~0u;

#define INS_STEP(A, B) { \
  const unsigned a_ = key_ > K##A ? key_ : K##A; \
  K##B = a_ < K##B ? a_ : K##B; }

#define INSKEY() { \
  INS_STEP(30,31) INS_STEP(29,30) INS_STEP(28,29) INS_STEP(27,28) \
  INS_STEP(26,27) INS_STEP(25,26) INS_STEP(24,25) INS_STEP(23,24) \
  INS_STEP(22,23) INS_STEP(21,22) INS_STEP(20,21) INS_STEP(19,20) \
  INS_STEP(18,19) INS_STEP(17,18) INS_STEP(16,17) INS_STEP(15,16) \
  INS_STEP(14,15) INS_STEP(13,14) INS_STEP(12,13) INS_STEP(11,12) \
  INS_STEP(10,11) INS_STEP(9,10)  INS_STEP(8,9)   INS_STEP(7,8) \
  INS_STEP(6,7)   INS_STEP(5,6)   INS_STEP(4,5)   INS_STEP(3,4) \
  INS_STEP(2,3)   INS_STEP(1,2)   INS_STEP(0,1) \
  K0 = key_ < K0 ? key_ : K0; }

#define LOADP(GT, PH, PL) { \
  const size_t bb_ = (size_t)((GT) * 4 + w) * 4096 + (size_t)lane * 16; \
  _Pragma("unroll") for (int s_ = 0; s_ < 4; ++s_) { \
    PH[s_] = *(const bfrag*)(xh + bb_ + s_ * 1024); \
    PL[s_] = *(const bfrag*)(xl + bb_ + s_ * 1024); } }

#define PIN(PH, PL) asm volatile("" :: "v"(PH[0]), "v"(PH[1]), "v"(PH[2]), "v"(PH[3]), \
                                       "v"(PL[0]), "v"(PL[1]), "v"(PL[2]), "v"(PL[3]));

#define MFMA12(A0, PH, PL) { \
  _Pragma("unroll") for (int s_ = 0; s_ < 4; ++s_) \
    A0 = __builtin_amdgcn_mfma_f32_32x32x16_bf16(PH[s_], qhi[s_], A0, 0, 0, 0); \
  _Pragma("unroll") for (int s_ = 0; s_ < 4; ++s_) \
    A0 = __builtin_amdgcn_mfma_f32_32x32x16_bf16(PH[s_], qlo[s_], A0, 0, 0, 0); \
  _Pragma("unroll") for (int s_ = 0; s_ < 4; ++s_) \
    A0 = __builtin_amdgcn_mfma_f32_32x32x16_bf16(PL[s_], qhi[s_], A0, 0, 0, 0); }

#define STEP(LT, PHc, PLc, PHn, PLn) { \
  const int gT_ = t0 + (LT); \
  if ((LT) + 1 < 64) LOADP(gT_ + 1, PHn, PLn) \
  f32x16 a0_; \
  _Pragma("unroll") for (int i_ = 0; i_ < 16; ++i_) a0_[i_] = 0.f; \
  MFMA12(a0_, PHc, PLc) \
  PIN(PHn, PLn) \
  const float* sb_ = sq + gT_ * 128 + w * 32 + 4 * h; \
  const bool selfHere_ = (gT_ == selfTl) && (w == selfW); \
  const int pb_ = gT_ * 128 + w * 32 + 4 * h; \
  _Pragma("unroll") for (int g_ = 0; g_ < 4; ++g_) { \
    const float4 sv_ = *(const float4*)(sb_ + g_ * 8); \
    const float sg_[4] = {sv_.x, sv_.y, sv_.z, sv_.w}; \
    _Pragma("unroll") for (int u_ = 0; u_ < 4; ++u_) { \
      const int r_ = g_ * 4 + u_; \
      float d2_ = fmaf(-2.0f, a0_[r_], sqq + sg_[u_]); \
      if (selfHere_ && h == selfH && r_ == selfR) d2_ = 1e30f; \
      unsigned dq_ = (unsigned)(d2_ * 256.0f); \
      dq_ = dq_ > 0x3FFEFu ? 0x3FFEFu : dq_; \
      const unsigned key_ = (dq_ << 14) | (unsigned)(pb_ + r_ + (r_ & ~3)); \
      if (__any(key_ < K31)) INSKEY() \
    } } }

  bfrag phA[4], plA[4], phB[4], plB[4];
  LOADP(t0, phA, plA) PIN(phA, plA)
  for (int lt = 0; lt < 62; lt += 2) {
    STEP(lt, phA, plA, phB, plB)
    STEP(lt + 1, phB, plB, phA, plA)
  }
  STEP(62, phA, plA, phB, plB)
  STEP(63, phB, plB, phA, plA)

  // dump sorted register lists to LDS for the in-block merge
  {
    unsigned* ml = &tk[t * LSTR];
    ml[0]=K0; ml[1]=K1; ml[2]=K2; ml[3]=K3; ml[4]=K4; ml[5]=K5; ml[6]=K6; ml[7]=K7;
    ml[8]=K8; ml[9]=K9; ml[10]=K10; ml[11]=K11; ml[12]=K12; ml[13]=K13; ml[14]=K14; ml[15]=K15;
    ml[16]=K16; ml[17]=K17; ml[18]=K18; ml[19]=K19; ml[20]=K20; ml[21]=K21; ml[22]=K22; ml[23]=K23;
    ml[24]=K24; ml[25]=K25; ml[26]=K26; ml[27]=K27; ml[28]=K28; ml[29]=K29; ml[30]=K30; ml[31]=K31;
  }
  __syncthreads();

  // ---- in-block merge: 8 lane-lists -> sorted top-32/query -> part ----
#define SORT64(V) { \
  _Pragma("unroll") for (int k_ = 2; k_ <= 64; k_ <<= 1) { \
    _Pragma("unroll") for (int j_ = k_ >> 1; j_ >= 1; j_ >>= 1) { \
      const unsigned o_ = (unsigned)__shfl_xor((int)V, j_); \
      const bool km_ = ((lane & j_) == 0) == ((lane & k_) == 0); \
      V = km_ ? (V < o_ ? V : o_) : (V > o_ ? V : o_); \
    } } }

#define MERGE6(V) { \
  _Pragma("unroll") for (int j_ = 32; j_ >= 1; j_ >>= 1) { \
    const unsigned o_ = (unsigned)__shfl_xor((int)V, j_); \
    const bool km_ = ((lane & j_) == 0); \
    V = km_ ? (V < o_ ? V : o_) : (V > o_ ? V : o_); \
  } }

  unsigned* S = &ms[w * 128];
  for (int s8 = 0; s8 < 8; ++s8) {
    const int qq = w * 8 + s8;
#pragma unroll
    for (int w2 = 0; w2 < 4; ++w2) {
      unsigned v = tk[(w2 * 64 + (lane & 32) + qq) * LSTR + (lane & 31)];
      SORT64(v)
      if (lane < 32) S[w2 * 32 + lane] = v;
    }
    {
      unsigned v = (lane < 32) ? S[0 * 32 + lane] : S[1 * 32 + (63 - lane)];
      MERGE6(v)
      if (lane < 32) S[0 * 32 + lane] = v;
    }
    {
      unsigned v = (lane < 32) ? S[2 * 32 + lane] : S[3 * 32 + (63 - lane)];
      MERGE6(v)
      if (lane < 32) S[2 * 32 + lane] = v;
    }
    {
      unsigned v = (lane < 32) ? S[0 * 32 + lane] : S[2 * 32 + (63 - lane)];
      MERGE6(v)
      if (lane < 32)
        part[(size_t)(qg0 + qq) * 64 + half * 32 + lane] = v;
    }
  }
#undef INS_STEP
#undef INSKEY
#undef LOADP
#undef PIN
#undef MFMA12
#undef STEP
#undef SORT64
#undef MERGE6
}

// ---------------- KNN pass 2: merge two sorted-32 lists + softmax ----------------
__global__ __launch_bounds__(256) void k_merge(const unsigned* __restrict__ part,
    unsigned short* __restrict__ nidx, float* __restrict__ nw) {
  const int t = threadIdx.x;
  const int w = t >> 6;
  const int lane = t & 63;
  const int q = (int)blockIdx.x * 4 + w;
  const int src = (lane < 32) ? lane : (95 - lane);
  unsigned v = part[(size_t)q * 64 + src];
#pragma unroll
  for (int j = 32; j >= 1; j >>= 1) {
    const unsigned o = (unsigned)__shfl_xor((int)v, j);
    const bool mn = ((lane & j) == 0);
    v = mn ? (v < o ? v : o) : (v > o ? v : o);
  }
  const float d = sqrtf((float)(v >> 14) * (1.0f / 256.0f));
  const float dmin = __shfl(d, 0);
  float e = (lane < 32) ? __expf((dmin - d) * 2.0f) : 0.f;
  float s2 = e;
#pragma unroll
  for (int m = 1; m < 64; m <<= 1) s2 += __shfl_xor(s2, m);
  if (lane < 32) {
    nw[(size_t)q * Kk + lane] = e / s2;
    nidx[(size_t)q * Kk + lane] = (unsigned short)(v & 0x3FFFu);
  }
}

// ---------------- one message-pass step, fused: gather+MLP+LN ----------------
#define RB 32
#define US 36

__global__ __launch_bounds__(256) void k_step(const float* __restrict__ x,
    const float* __restrict__ hin, const unsigned short* __restrict__ nidx,
    const float* __restrict__ nw, const float* __restrict__ Wm1,
    const float* __restrict__ bm1, const float* __restrict__ Wm2,
    const float* __restrict__ bm2, const float* __restrict__ g,
    const float* __restrict__ be, float* __restrict__ hout) {
  __shared__ float updT[2 * Hd + Fd][US];  // upd_in transposed: 320 x 36 (46 KB)
  __shared__ float t1T[Hd][US];            // silu(GEMM1) transposed (18 KB)
  const int t = threadIdx.x;
  const int r0 = blockIdx.x * RB;

  { // stage: hidden | agg (gather) | x, all transposed
    const int r = t >> 3, s = t & 7;
    const int i = r0 + r;
    const float* hr = hin + (size_t)i * Hd + (s << 4);
#pragma unroll
    for (int u = 0; u < 4; ++u) {
      float4 v = *(const float4*)(hr + (u << 2));
      const int c = (s << 4) + (u << 2);
      updT[c + 0][r] = v.x; updT[c + 1][r] = v.y;
      updT[c + 2][r] = v.z; updT[c + 3][r] = v.w;
    }
    float a[16];
#pragma unroll
    for (int u = 0; u < 16; ++u) a[u] = 0.f;
    const unsigned short* ir = nidx + i * Kk;
    const float* wr = nw + i * Kk;
    for (int k = 0; k < Kk; ++k) {
      const float wk = wr[k];
      const float* hv = hin + (size_t)ir[k] * Hd + (s << 4);
#pragma unroll
      for (int u = 0; u < 4; ++u) {
        float4 v = *(const float4*)(hv + (u << 2));
        a[(u << 2) + 0] = fmaf(wk, v.x, a[(u << 2) + 0]);
        a[(u << 2) + 1] = fmaf(wk, v.y, a[(u << 2) + 1]);
        a[(u << 2) + 2] = fmaf(wk, v.z, a[(u << 2) + 2]);
        a[(u << 2) + 3] = fmaf(wk, v.w, a[(u << 2) + 3]);
      }
    }
#pragma unroll
    for (int u = 0; u < 16; ++u) updT[Hd + (s << 4) + u][r] = a[u];
    const float* xr = x + (size_t)i * Fd + (s << 3);
    float4 x0 = *(const float4*)(xr);
    float4 x1 = *(const float4*)(xr + 4);
    const int c = 2 * Hd + (s << 3);
    updT[c + 0][r] = x0.x; updT[c + 1][r] = x0.y;
    updT[c + 2][r] = x0.z; updT[c + 3][r] = x0.w;
    updT[c + 4][r] = x1.x; updT[c + 5][r] = x1.y;
    updT[c + 6][r] = x1.z; updT[c + 7][r] = x1.w;
  }
  __syncthreads();

  const int rg = t >> 5, cg = t & 31;
  const int rr = rg << 2, cc = cg << 2;
  { // GEMM1 [32x320]x[320x128] + silu -> t1T
    float acc[4][4] = {};
#pragma unroll 4
    for (int k = 0; k < 2 * Hd + Fd; ++k) {
      float4 uv = *(const float4*)&updT[k][rr];
      float4 wv = *(const float4*)&Wm1[k * Hd + cc];
      FMA16(acc, uv, wv)
    }
    float4 b1 = *(const float4*)&bm1[cc];
    float bb1[4] = {b1.x, b1.y, b1.z, b1.w};
#pragma unroll
    for (int a = 0; a < 4; ++a)
#pragma unroll
      for (int b = 0; b < 4; ++b) {
        const float z = acc[a][b] + bb1[b];
        t1T[cc + b][rr + a] = z / (1.0f + __expf(-z));
      }
  }
  __syncthreads();
  { // GEMM2 [32x128]x[128x128] + residual + LayerNorm
    float acc[4][4] = {};
#pragma unroll 4
    for (int k = 0; k < Hd; ++k) {
      float4 uv = *(const float4*)&t1T[k][rr];
      float4 wv = *(const float4*)&Wm2[k * Hd + cc];
      FMA16(acc, uv, wv)
    }
    float4 b2 = *(const float4*)&bm2[cc];
    float bb2[4] = {b2.x, b2.y, b2.z, b2.w};
    float v[4][4];
#pragma unroll
    for (int b = 0; b < 4; ++b) {
      float4 hres = *(const float4*)&updT[cc + b][rr];  // residual = staged hidden
      v[0][b] = hres.x + acc[0][b] + bb2[b];
      v[1][b] = hres.y + acc[1][b] + bb2[b];
      v[2][b] = hres.z + acc[2][b] + bb2[b];
      v[3][b] = hres.w + acc[3][b] + bb2[b];
    }
    float4 gv = *(const float4*)&g[cc];
    float4 bev = *(const float4*)&be[cc];
    float gg[4] = {gv.x, gv.y, gv.z, gv.w};
    float eb[4] = {bev.x, bev.y, bev.z, bev.w};
#pragma unroll
    for (int a = 0; a < 4; ++a) {
      float sm = v[a][0] + v[a][1] + v[a][2] + v[a][3];
      float s2 = 0.f;
#pragma unroll
      for (int b = 0; b < 4; ++b) s2 = fmaf(v[a][b], v[a][b], s2);
#pragma unroll
      for (int m = 1; m < 32; m <<= 1) {
        sm += __shfl_xor(sm, m);
        s2 += __shfl_xor(s2, m);
      }
      const float mean = sm * (1.0f / 128.0f);
      const float var = fmaxf(s2 * (1.0f / 128.0f) - mean * mean, 0.0f);
      const float rstd = rsqrtf(var + 1e-5f);
      float4 o;
      o.x = (v[a][0] - mean) * rstd * gg[0] + eb[0];
      o.y = (v[a][1] - mean) * rstd * gg[1] + eb[1];
      o.z = (v[a][2] - mean) * rstd * gg[2] + eb[2];
      o.w = (v[a][3] - mean) * rstd * gg[3] + eb[3];
      *(float4*)&hout[(size_t)(r0 + rr + a) * Hd + cc] = o;
    }
  }
}

// ---------------- readout: softplus(silu([h,x]@Wr1+b)@Wr2+b) ----------------
__global__ __launch_bounds__(256) void k_out(const float* __restrict__ x,
    const float* __restrict__ hin, const float* __restrict__ Wr1,
    const float* __restrict__ br1, const float* __restrict__ Wr2,
    const float* __restrict__ br2, float* __restrict__ out) {
  __shared__ float rT[Hd + Fd][US];  // 192 x 36 (27 KB)
  const int t = threadIdx.x;
  const int r0 = blockIdx.x * RB;
  {
    const int r = t >> 3, s = t & 7;
    const int i = r0 + r;
    const float* hr = hin + (size_t)i * Hd + (s << 4);
#pragma unroll
    for (int u = 0; u < 4; ++u) {
      float4 v = *(const float4*)(hr + (u << 2));
      const int c = (s << 4) + (u << 2);
      rT[c + 0][r] = v.x; rT[c + 1][r] = v.y;
      rT[c + 2][r] = v.z; rT[c + 3][r] = v.w;
    }
    const float* xr = x + (size_t)i * Fd + (s << 3);
    float4 x0 = *(const float4*)(xr);
    float4 x1 = *(const float4*)(xr + 4);
    const int c = Hd + (s << 3);
    rT[c + 0][r] = x0.x; rT[c + 1][r] = x0.y;
    rT[c + 2][r] = x0.z; rT[c + 3][r] = x0.w;
    rT[c + 4][r] = x1.x; rT[c + 5][r] = x1.y;
    rT[c + 6][r] = x1.z; rT[c + 7][r] = x1.w;
  }
  __syncthreads();
  const int rg = t >> 5, cg = t & 31;
  const int rr = rg << 2, cc = cg << 2;
  float acc[4][4] = {};
#pragma unroll 4
  for (int k = 0; k < Hd + Fd; ++k) {
    float4 uv = *(const float4*)&rT[k][rr];
    float4 wv = *(const float4*)&Wr1[k * Hd + cc];
    FMA16(acc, uv, wv)
  }
  float4 b1 = *(const float4*)&br1[cc];
  float bb1[4] = {b1.x, b1.y, b1.z, b1.w};
  float4 w2 = *(const float4*)&Wr2[cc];
  float ww[4] = {w2.x, w2.y, w2.z, w2.w};
  float part[4];
#pragma unroll
  for (int a = 0; a < 4; ++a) {
    part[a] = 0.f;
#pragma unroll
    for (int b = 0; b < 4; ++b) {
      const float z = acc[a][b] + bb1[b];
      const float sil = z / (1.0f + __expf(-z));
      part[a] = fmaf(sil, ww[b], part[a]);
    }
  }
#pragma unroll
  for (int m = 1; m < 32; m <<= 1) {
#pragma unroll
    for (int a = 0; a < 4; ++a) part[a] += __shfl_xor(part[a], m);
  }
  if (cg == 0) {
    const float bias = br2[0];
#pragma unroll
    for (int a = 0; a < 4; ++a) {
      const float rv = part[a] + bias;
      out[r0 + rr + a] = fmaxf(rv, 0.0f) + log1pf(__expf(-fabsf(rv)));
    }
  }
}

extern "C" void kernel_launch(void* const* d_in, const int* in_sizes, int n_in,
                              void* d_out, int out_size, void* d_ws, size_t ws_size,
                              hipStream_t stream) {
  const float* x    = (const float*)d_in[0];
  const float* W_in = (const float*)d_in[1];
  const float* b_in = (const float*)d_in[2];
  const float* W_m1 = (const float*)d_in[3];
  const float* b_m1 = (const float*)d_in[4];
  const float* W_m2 = (const float*)d_in[5];
  const float* b_m2 = (const float*)d_in[6];
  const float* ln_g = (const float*)d_in[7];
  const float* ln_b = (const float*)d_in[8];
  const float* W_r1 = (const float*)d_in[9];
  const float* b_r1 = (const float*)d_in[10];
  const float* W_r2 = (const float*)d_in[11];
  const float* b_r2 = (const float*)d_in[12];
  float* out = (float*)d_out;

  char* ws = (char*)d_ws;
  const size_t MB = (size_t)1 << 20;
  float*          hidA = (float*)(ws);                 // 8 MB
  float*          hidB = (float*)(ws + 8 * MB);        // 8 MB (aliases partbuf)
  unsigned*       partb = (unsigned*)(ws + 8 * MB);    // 4 MB, dead before hidB use
  short*          xbhi = (short*)(ws + 16 * MB);       // 2 MB
  short*          xblo = (short*)(ws + 18 * MB);       // 2 MB
  unsigned short* nidx = (unsigned short*)(ws + 20 * MB);  // 1 MB
  float*          nw   = (float*)(ws + 21 * MB);       // 2 MB
  float*          sq   = (float*)(ws + 23 * MB);       // 64 KB

  k_input<<<dim3(Nn / 2), dim3(256), 0, stream>>>(x, W_in, b_in, hidA, sq);
  k_prep<<<dim3(Nn * 8 / 256), dim3(256), 0, stream>>>(x, xbhi, xblo);
  k_knn<<<dim3(Nn / 32 * 2), dim3(256), 0, stream>>>(xbhi, xblo, sq, partb);
  k_merge<<<dim3(Nn / 4), dim3(256), 0, stream>>>(partb, nidx, nw);
  k_step<<<dim3(Nn / RB), dim3(256), 0, stream>>>(x, hidA, nidx, nw, W_m1, b_m1,
                                                  W_m2, b_m2, ln_g, ln_b, hidB);
  k_step<<<dim3(Nn / RB), dim3(256), 0, stream>>>(x, hidB, nidx, nw, W_m1, b_m1,
                                                  W_m2, b_m2, ln_g, ln_b, hidA);
  k_out<<<dim3(Nn / RB), dim3(256), 0, stream>>>(x, hidA, W_r1, b_r1, W_r2, b_r2, out);
}

// Round 15
// 464.398 us; speedup vs baseline: 1.5605x; 1.5550x over previous
//
#include <hip/hip_runtime.h>
#include <math.h>

#define Nn 16384
#define Fd 64
#define Hd 128
#define Kk 32

typedef short bfrag __attribute__((ext_vector_type(8)));    // 8 bf16 = 4 VGPR
typedef float f32x16 __attribute__((ext_vector_type(16)));  // MFMA 32x32 acc

#define FMA16(acc, qv, pv) \
  acc[0][0]=fmaf(qv.x,pv.x,acc[0][0]); acc[0][1]=fmaf(qv.x,pv.y,acc[0][1]); \
  acc[0][2]=fmaf(qv.x,pv.z,acc[0][2]); acc[0][3]=fmaf(qv.x,pv.w,acc[0][3]); \
  acc[1][0]=fmaf(qv.y,pv.x,acc[1][0]); acc[1][1]=fmaf(qv.y,pv.y,acc[1][1]); \
  acc[1][2]=fmaf(qv.y,pv.z,acc[1][2]); acc[1][3]=fmaf(qv.y,pv.w,acc[1][3]); \
  acc[2][0]=fmaf(qv.z,pv.x,acc[2][0]); acc[2][1]=fmaf(qv.z,pv.y,acc[2][1]); \
  acc[2][2]=fmaf(qv.z,pv.z,acc[2][2]); acc[2][3]=fmaf(qv.z,pv.w,acc[2][3]); \
  acc[3][0]=fmaf(qv.w,pv.x,acc[3][0]); acc[3][1]=fmaf(qv.w,pv.y,acc[3][1]); \
  acc[3][2]=fmaf(qv.w,pv.z,acc[3][2]); acc[3][3]=fmaf(qv.w,pv.w,acc[3][3]);

// ---------------- hidden0 = x @ W_in + b_in ; sq[i] = sum(x_i^2) ----------------
__global__ __launch_bounds__(256) void k_input(const float* __restrict__ x,
    const float* __restrict__ W, const float* __restrict__ b,
    float* __restrict__ hid, float* __restrict__ sq) {
  const int t = threadIdx.x;
  const int i = (blockIdx.x << 1) + (t >> 7);
  const int h = t & 127;
  const float* xr = x + (size_t)i * Fd;
  float acc = 0.f, s = 0.f;
#pragma unroll 8
  for (int f = 0; f < Fd; ++f) {
    float xv = xr[f];
    acc = fmaf(xv, W[f * Hd + h], acc);
    s = fmaf(xv, xv, s);
  }
  hid[(size_t)i * Hd + h] = acc + b[h];
  if (h == 0) sq[i] = s;
}

// ------------- precompute x as bf16 hi/lo in MFMA-fragment order -------------
__global__ __launch_bounds__(256) void k_prep(const float* __restrict__ x,
    short* __restrict__ xh, short* __restrict__ xl) {
  const int gid = blockIdx.x * 256 + threadIdx.x;
  const int p = gid >> 3, sub = gid & 7;
  const float* src = x + (size_t)p * Fd + sub * 8;
  float4 v0 = *(const float4*)src;
  float4 v1 = *(const float4*)(src + 4);
  float vv[8] = {v0.x, v0.y, v0.z, v0.w, v1.x, v1.y, v1.z, v1.w};
  bfrag hi, lo;
#pragma unroll
  for (int j = 0; j < 8; ++j) {
    unsigned u = __float_as_uint(vv[j]);
    unsigned r = u + 0x7fffu + ((u >> 16) & 1u);
    unsigned short hb = (unsigned short)(r >> 16);
    float hf = __uint_as_float((unsigned)hb << 16);
    float lof = vv[j] - hf;
    unsigned ul = __float_as_uint(lof);
    unsigned rl = ul + 0x7fffu + ((ul >> 16) & 1u);
    hi[j] = (short)hb;
    lo[j] = (short)(rl >> 16);
  }
  const size_t o = (size_t)(p >> 5) * 2048 + (size_t)sub * 256 + (size_t)(p & 31) * 8;
  *(bfrag*)(xh + o) = hi;
  *(bfrag*)(xl + o) = lo;
}

// ---------------- KNN pass 1: split-K, batched sorting-network top-32 ----------------
// Grid 1024: (qblk = bid>>1, half = bid&1), 64 tiles of 128 pts each.
// mfma(A=points, B=queries): lane (q=lane&31, h=lane>>5) holds 16 pt-dists of ITS
// query in regs. Per tile: pack 16 keys -> C0..C15, odd-even-mergesort-16 (63 CE),
// top-k merge into sorted K0..K31: 16x K[31-i]=min(K[31-i],C[i]) (exact, keeps 32
// smallest; leaves K bitonic), bitonic-merge-32 resort (80 CE). Constant cost,
// branch-free, pure function of key multiset -> deterministic.
#define LSTR 33

__global__ __launch_bounds__(256, 2) void k_knn(const short* __restrict__ xbhi,
    const short* __restrict__ xblo, const float* __restrict__ sq,
    unsigned* __restrict__ part) {
  __shared__ unsigned tk[256 * LSTR];   // final-merge staging only (33.8 KB)
  __shared__ unsigned ms[512];          // merge scratch (2 KB)

  const int t = threadIdx.x;
  const int w = t >> 6;
  const int lane = t & 63;
  const int h = lane >> 5;
  const int q = lane & 31;
  const int qblk = (int)(blockIdx.x >> 1);
  const int half = (int)(blockIdx.x & 1);
  const int qg0 = qblk * 32;
  const int t0 = half * 64;
  const int selfq = qg0 + q;
  const float sqq = sq[selfq];
  const int selfTl = qg0 >> 7;            // wave-uniform
  const int selfW = (qg0 >> 5) & 3;       // wave-uniform
  const int selfH = (q >> 2) & 1;
  const int selfR = (q & 3) + 4 * (q >> 3);

  const char* xh = (const char*)xbhi;
  const char* xl = (const char*)xblo;

  bfrag qhi[4], qlo[4];
  {
    const size_t a0 = (size_t)qblk * 4096 + (size_t)lane * 16;
#pragma unroll
    for (int s = 0; s < 4; ++s) {
      qhi[s] = *(const bfrag*)(xh + a0 + s * 1024);
      qlo[s] = *(const bfrag*)(xl + a0 + s * 1024);
    }
  }
  asm volatile("" :: "v"(qhi[0]), "v"(qhi[1]), "v"(qhi[2]), "v"(qhi[3]),
                     "v"(qlo[0]), "v"(qlo[1]), "v"(qlo[2]), "v"(qlo[3]));

  // sorted ascending top-32, named registers; init = +inf keys
  unsigned K0=~0u,K1=~0u,K2=~0u,K3=~0u,K4=~0u,K5=~0u,K6=~0u,K7=~0u,
           K8=~0u,K9=~0u,K10=~0u,K11=~0u,K12=~0u,K13=~0u,K14=~0u,K15=~0u,
           K16=~0u,K17=~0u,K18=~0u,K19=~0u,K20=~0u,K21=~0u,K22=~0u,K23=~0u,
           K24=~0u,K25=~0u,K26=~0u,K27=~0u,K28=~0u,K29=~0u,K30=~0u,K31=~0u;

  // compare-exchange: min -> lower index
#define CEC(A,B) { const unsigned x_=C##A, y_=C##B; \
  C##A = x_ < y_ ? x_ : y_; C##B = x_ < y_ ? y_ : x_; }
#define CEK(A,B) { const unsigned x_=K##A, y_=K##B; \
  K##A = x_ < y_ ? x_ : y_; K##B = x_ < y_ ? y_ : x_; }

  // Batcher odd-even mergesort-16 on C0..C15 (63 CE, verified network)
#define SORT16C \
  CEC(0,1) CEC(2,3) CEC(4,5) CEC(6,7) CEC(8,9) CEC(10,11) CEC(12,13) CEC(14,15) \
  CEC(0,2) CEC(1,3) CEC(4,6) CEC(5,7) CEC(8,10) CEC(9,11) CEC(12,14) CEC(13,15) \
  CEC(1,2) CEC(5,6) CEC(9,10) CEC(13,14) \
  CEC(0,4) CEC(1,5) CEC(2,6) CEC(3,7) CEC(8,12) CEC(9,13) CEC(10,14) CEC(11,15) \
  CEC(2,4) CEC(3,5) CEC(10,12) CEC(11,13) \
  CEC(1,2) CEC(3,4) CEC(5,6) CEC(9,10) CEC(11,12) CEC(13,14) \
  CEC(0,8) CEC(1,9) CEC(2,10) CEC(3,11) CEC(4,12) CEC(5,13) CEC(6,14) CEC(7,15) \
  CEC(4,8) CEC(5,9) CEC(6,10) CEC(7,11) \
  CEC(2,4) CEC(3,5) CEC(6,8) CEC(7,9) CEC(10,12) CEC(11,13) \
  CEC(1,2) CEC(3,4) CEC(5,6) CEC(7,8) CEC(9,10) CEC(11,12) CEC(13,14)

  // top-k merge: K[31-i] = min(K[31-i], C[i]) — keeps 32 smallest, K becomes bitonic
#define HC(A,B) { K##A = C##B < K##A ? C##B : K##A; }
#define HALFCLEAN \
  HC(31,0) HC(30,1) HC(29,2) HC(28,3) HC(27,4) HC(26,5) HC(25,6) HC(24,7) \
  HC(23,8) HC(22,9) HC(21,10) HC(20,11) HC(19,12) HC(18,13) HC(17,14) HC(16,15)

  // bitonic merge-32 (sorts any bitonic sequence ascending; 80 CE)
#define RESORT32 \
  CEK(0,16) CEK(1,17) CEK(2,18) CEK(3,19) CEK(4,20) CEK(5,21) CEK(6,22) CEK(7,23) \
  CEK(8,24) CEK(9,25) CEK(10,26) CEK(11,27) CEK(12,28) CEK(13,29) CEK(14,30) CEK(15,31) \
  CEK(0,8) CEK(1,9) CEK(2,10) CEK(3,11) CEK(4,12) CEK(5,13) CEK(6,14) CEK(7,15) \
  CEK(16,24) CEK(17,25) CEK(18,26) CEK(19,27) CEK(20,28) CEK(21,29) CEK(22,30) CEK(23,31) \
  CEK(0,4) CEK(1,5) CEK(2,6) CEK(3,7) CEK(8,12) CEK(9,13) CEK(10,14) CEK(11,15) \
  CEK(16,20) CEK(17,21) CEK(18,22) CEK(19,23) CEK(24,28) CEK(25,29) CEK(26,30) CEK(27,31) \
  CEK(0,2) CEK(1,3) CEK(4,6) CEK(5,7) CEK(8,10) CEK(9,11) CEK(12,14) CEK(13,15) \
  CEK(16,18) CEK(17,19) CEK(20,22) CEK(21,23) CEK(24,26) CEK(25,27) CEK(28,30) CEK(29,31) \
  CEK(0,1) CEK(2,3) CEK(4,5) CEK(6,7) CEK(8,9) CEK(10,11) CEK(12,13) CEK(14,15) \
  CEK(16,17) CEK(18,19) CEK(20,21) CEK(22,23) CEK(24,25) CEK(26,27) CEK(28,29) CEK(30,31)

#define LOADP(GT, PH, PL) { \
  const size_t bb_ = (size_t)((GT) * 4 + w) * 4096 + (size_t)lane * 16; \
  _Pragma("unroll") for (int s_ = 0; s_ < 4; ++s_) { \
    PH[s_] = *(const bfrag*)(xh + bb_ + s_ * 1024); \
    PL[s_] = *(const bfrag*)(xl + bb_ + s_ * 1024); } }

#define PIN(PH, PL) asm volatile("" :: "v"(PH[0]), "v"(PH[1]), "v"(PH[2]), "v"(PH[3]), \
                                       "v"(PL[0]), "v"(PL[1]), "v"(PL[2]), "v"(PL[3]));

#define MFMA12(A0, PH, PL) { \
  _Pragma("unroll") for (int s_ = 0; s_ < 4; ++s_) \
    A0 = __builtin_amdgcn_mfma_f32_32x32x16_bf16(PH[s_], qhi[s_], A0, 0, 0, 0); \
  _Pragma("unroll") for (int s_ = 0; s_ < 4; ++s_) \
    A0 = __builtin_amdgcn_mfma_f32_32x32x16_bf16(PH[s_], qlo[s_], A0, 0, 0, 0); \
  _Pragma("unroll") for (int s_ = 0; s_ < 4; ++s_) \
    A0 = __builtin_amdgcn_mfma_f32_32x32x16_bf16(PL[s_], qhi[s_], A0, 0, 0, 0); }

#define MKKEY(R, SV) { \
  float d2_ = fmaf(-2.0f, a0_[R], sqq + (SV)); \
  if (selfHere_ && h == selfH && (R) == selfR) d2_ = 1e30f; \
  unsigned dq_ = (unsigned)(d2_ * 256.0f); \
  dq_ = dq_ > 0x3FFEFu ? 0x3FFEFu : dq_; \
  C##R = (dq_ << 14) | (unsigned)(pb_ + (R) + ((R) & ~3)); }

#define STEP(LT, PHc, PLc, PHn, PLn) { \
  const int gT_ = t0 + (LT); \
  if ((LT) + 1 < 64) LOADP(gT_ + 1, PHn, PLn) \
  f32x16 a0_; \
  _Pragma("unroll") for (int i_ = 0; i_ < 16; ++i_) a0_[i_] = 0.f; \
  MFMA12(a0_, PHc, PLc) \
  PIN(PHn, PLn) \
  const float* sb_ = sq + gT_ * 128 + w * 32 + 4 * h; \
  const float4 s0_ = *(const float4*)(sb_); \
  const float4 s1_ = *(const float4*)(sb_ + 8); \
  const float4 s2_ = *(const float4*)(sb_ + 16); \
  const float4 s3_ = *(const float4*)(sb_ + 24); \
  const bool selfHere_ = (gT_ == selfTl) && (w == selfW); \
  const int pb_ = gT_ * 128 + w * 32 + 4 * h; \
  unsigned C0,C1,C2,C3,C4,C5,C6,C7,C8,C9,C10,C11,C12,C13,C14,C15; \
  MKKEY(0, s0_.x) MKKEY(1, s0_.y) MKKEY(2, s0_.z) MKKEY(3, s0_.w) \
  MKKEY(4, s1_.x) MKKEY(5, s1_.y) MKKEY(6, s1_.z) MKKEY(7, s1_.w) \
  MKKEY(8, s2_.x) MKKEY(9, s2_.y) MKKEY(10, s2_.z) MKKEY(11, s2_.w) \
  MKKEY(12, s3_.x) MKKEY(13, s3_.y) MKKEY(14, s3_.z) MKKEY(15, s3_.w) \
  SORT16C \
  HALFCLEAN \
  RESORT32 }

  bfrag phA[4], plA[4], phB[4], plB[4];
  LOADP(t0, phA, plA) PIN(phA, plA)
  for (int lt = 0; lt < 62; lt += 2) {
    STEP(lt, phA, plA, phB, plB)
    STEP(lt + 1, phB, plB, phA, plA)
  }
  STEP(62, phA, plA, phB, plB)
  STEP(63, phB, plB, phA, plA)

  // dump sorted register lists to LDS for the in-block merge
  {
    unsigned* ml = &tk[t * LSTR];
    ml[0]=K0; ml[1]=K1; ml[2]=K2; ml[3]=K3; ml[4]=K4; ml[5]=K5; ml[6]=K6; ml[7]=K7;
    ml[8]=K8; ml[9]=K9; ml[10]=K10; ml[11]=K11; ml[12]=K12; ml[13]=K13; ml[14]=K14; ml[15]=K15;
    ml[16]=K16; ml[17]=K17; ml[18]=K18; ml[19]=K19; ml[20]=K20; ml[21]=K21; ml[22]=K22; ml[23]=K23;
    ml[24]=K24; ml[25]=K25; ml[26]=K26; ml[27]=K27; ml[28]=K28; ml[29]=K29; ml[30]=K30; ml[31]=K31;
  }
  __syncthreads();

  // ---- in-block merge: 8 lane-lists -> sorted top-32/query -> part ----
#define SORT64(V) { \
  _Pragma("unroll") for (int k_ = 2; k_ <= 64; k_ <<= 1) { \
    _Pragma("unroll") for (int j_ = k_ >> 1; j_ >= 1; j_ >>= 1) { \
      const unsigned o_ = (unsigned)__shfl_xor((int)V, j_); \
      const bool km_ = ((lane & j_) == 0) == ((lane & k_) == 0); \
      V = km_ ? (V < o_ ? V : o_) : (V > o_ ? V : o_); \
    } } }

#define MERGE6(V) { \
  _Pragma("unroll") for (int j_ = 32; j_ >= 1; j_ >>= 1) { \
    const unsigned o_ = (unsigned)__shfl_xor((int)V, j_); \
    const bool km_ = ((lane & j_) == 0); \
    V = km_ ? (V < o_ ? V : o_) : (V > o_ ? V : o_); \
  } }

  unsigned* S = &ms[w * 128];
  for (int s8 = 0; s8 < 8; ++s8) {
    const int qq = w * 8 + s8;
#pragma unroll
    for (int w2 = 0; w2 < 4; ++w2) {
      unsigned v = tk[(w2 * 64 + (lane & 32) + qq) * LSTR + (lane & 31)];
      SORT64(v)
      if (lane < 32) S[w2 * 32 + lane] = v;
    }
    {
      unsigned v = (lane < 32) ? S[0 * 32 + lane] : S[1 * 32 + (63 - lane)];
      MERGE6(v)
      if (lane < 32) S[0 * 32 + lane] = v;
    }
    {
      unsigned v = (lane < 32) ? S[2 * 32 + lane] : S[3 * 32 + (63 - lane)];
      MERGE6(v)
      if (lane < 32) S[2 * 32 + lane] = v;
    }
    {
      unsigned v = (lane < 32) ? S[0 * 32 + lane] : S[2 * 32 + (63 - lane)];
      MERGE6(v)
      if (lane < 32)
        part[(size_t)(qg0 + qq) * 64 + half * 32 + lane] = v;
    }
  }
#undef CEC
#undef CEK
#undef SORT16C
#undef HC
#undef HALFCLEAN
#undef RESORT32
#undef LOADP
#undef PIN
#undef MFMA12
#undef MKKEY
#undef STEP
#undef SORT64
#undef MERGE6
}

// ---------------- KNN pass 2: merge two sorted-32 lists + softmax ----------------
__global__ __launch_bounds__(256) void k_merge(const unsigned* __restrict__ part,
    unsigned short* __restrict__ nidx, float* __restrict__ nw) {
  const int t = threadIdx.x;
  const int w = t >> 6;
  const int lane = t & 63;
  const int q = (int)blockIdx.x * 4 + w;
  const int src = (lane < 32) ? lane : (95 - lane);
  unsigned v = part[(size_t)q * 64 + src];
#pragma unroll
  for (int j = 32; j >= 1; j >>= 1) {
    const unsigned o = (unsigned)__shfl_xor((int)v, j);
    const bool mn = ((lane & j) == 0);
    v = mn ? (v < o ? v : o) : (v > o ? v : o);
  }
  const float d = sqrtf((float)(v >> 14) * (1.0f / 256.0f));
  const float dmin = __shfl(d, 0);
  float e = (lane < 32) ? __expf((dmin - d) * 2.0f) : 0.f;
  float s2 = e;
#pragma unroll
  for (int m = 1; m < 64; m <<= 1) s2 += __shfl_xor(s2, m);
  if (lane < 32) {
    nw[(size_t)q * Kk + lane] = e / s2;
    nidx[(size_t)q * Kk + lane] = (unsigned short)(v & 0x3FFFu);
  }
}

// ---------------- one message-pass step, fused: gather+MLP+LN ----------------
#define RB 32
#define US 36

__global__ __launch_bounds__(256) void k_step(const float* __restrict__ x,
    const float* __restrict__ hin, const unsigned short* __restrict__ nidx,
    const float* __restrict__ nw, const float* __restrict__ Wm1,
    const float* __restrict__ bm1, const float* __restrict__ Wm2,
    const float* __restrict__ bm2, const float* __restrict__ g,
    const float* __restrict__ be, float* __restrict__ hout) {
  __shared__ float updT[2 * Hd + Fd][US];  // upd_in transposed: 320 x 36 (46 KB)
  __shared__ float t1T[Hd][US];            // silu(GEMM1) transposed (18 KB)
  const int t = threadIdx.x;
  const int r0 = blockIdx.x * RB;

  { // stage: hidden | agg (gather) | x, all transposed
    const int r = t >> 3, s = t & 7;
    const int i = r0 + r;
    const float* hr = hin + (size_t)i * Hd + (s << 4);
#pragma unroll
    for (int u = 0; u < 4; ++u) {
      float4 v = *(const float4*)(hr + (u << 2));
      const int c = (s << 4) + (u << 2);
      updT[c + 0][r] = v.x; updT[c + 1][r] = v.y;
      updT[c + 2][r] = v.z; updT[c + 3][r] = v.w;
    }
    float a[16];
#pragma unroll
    for (int u = 0; u < 16; ++u) a[u] = 0.f;
    const unsigned short* ir = nidx + i * Kk;
    const float* wr = nw + i * Kk;
    for (int k = 0; k < Kk; ++k) {
      const float wk = wr[k];
      const float* hv = hin + (size_t)ir[k] * Hd + (s << 4);
#pragma unroll
      for (int u = 0; u < 4; ++u) {
        float4 v = *(const float4*)(hv + (u << 2));
        a[(u << 2) + 0] = fmaf(wk, v.x, a[(u << 2) + 0]);
        a[(u << 2) + 1] = fmaf(wk, v.y, a[(u << 2) + 1]);
        a[(u << 2) + 2] = fmaf(wk, v.z, a[(u << 2) + 2]);
        a[(u << 2) + 3] = fmaf(wk, v.w, a[(u << 2) + 3]);
      }
    }
#pragma unroll
    for (int u = 0; u < 16; ++u) updT[Hd + (s << 4) + u][r] = a[u];
    const float* xr = x + (size_t)i * Fd + (s << 3);
    float4 x0 = *(const float4*)(xr);
    float4 x1 = *(const float4*)(xr + 4);
    const int c = 2 * Hd + (s << 3);
    updT[c + 0][r] = x0.x; updT[c + 1][r] = x0.y;
    updT[c + 2][r] = x0.z; updT[c + 3][r] = x0.w;
    updT[c + 4][r] = x1.x; updT[c + 5][r] = x1.y;
    updT[c + 6][r] = x1.z; updT[c + 7][r] = x1.w;
  }
  __syncthreads();

  const int rg = t >> 5, cg = t & 31;
  const int rr = rg << 2, cc = cg << 2;
  { // GEMM1 [32x320]x[320x128] + silu -> t1T
    float acc[4][4] = {};
#pragma unroll 4
    for (int k = 0; k < 2 * Hd + Fd; ++k) {
      float4 uv = *(const float4*)&updT[k][rr];
      float4 wv = *(const float4*)&Wm1[k * Hd + cc];
      FMA16(acc, uv, wv)
    }
    float4 b1 = *(const float4*)&bm1[cc];
    float bb1[4] = {b1.x, b1.y, b1.z, b1.w};
#pragma unroll
    for (int a = 0; a < 4; ++a)
#pragma unroll
      for (int b = 0; b < 4; ++b) {
        const float z = acc[a][b] + bb1[b];
        t1T[cc + b][rr + a] = z / (1.0f + __expf(-z));
      }
  }
  __syncthreads();
  { // GEMM2 [32x128]x[128x128] + residual + LayerNorm
    float acc[4][4] = {};
#pragma unroll 4
    for (int k = 0; k < Hd; ++k) {
      float4 uv = *(const float4*)&t1T[k][rr];
      float4 wv = *(const float4*)&Wm2[k * Hd + cc];
      FMA16(acc, uv, wv)
    }
    float4 b2 = *(const float4*)&bm2[cc];
    float bb2[4] = {b2.x, b2.y, b2.z, b2.w};
    float v[4][4];
#pragma unroll
    for (int b = 0; b < 4; ++b) {
      float4 hres = *(const float4*)&updT[cc + b][rr];  // residual = staged hidden
      v[0][b] = hres.x + acc[0][b] + bb2[b];
      v[1][b] = hres.y + acc[1][b] + bb2[b];
      v[2][b] = hres.z + acc[2][b] + bb2[b];
      v[3][b] = hres.w + acc[3][b] + bb2[b];
    }
    float4 gv = *(const float4*)&g[cc];
    float4 bev = *(const float4*)&be[cc];
    float gg[4] = {gv.x, gv.y, gv.z, gv.w};
    float eb[4] = {bev.x, bev.y, bev.z, bev.w};
#pragma unroll
    for (int a = 0; a < 4; ++a) {
      float sm = v[a][0] + v[a][1] + v[a][2] + v[a][3];
      float s2 = 0.f;
#pragma unroll
      for (int b = 0; b < 4; ++b) s2 = fmaf(v[a][b], v[a][b], s2);
#pragma unroll
      for (int m = 1; m < 32; m <<= 1) {
        sm += __shfl_xor(sm, m);
        s2 += __shfl_xor(s2, m);
      }
      const float mean = sm * (1.0f / 128.0f);
      const float var = fmaxf(s2 * (1.0f / 128.0f) - mean * mean, 0.0f);
      const float rstd = rsqrtf(var + 1e-5f);
      float4 o;
      o.x = (v[a][0] - mean) * rstd * gg[0] + eb[0];
      o.y = (v[a][1] - mean) * rstd * gg[1] + eb[1];
      o.z = (v[a][2] - mean) * rstd * gg[2] + eb[2];
      o.w = (v[a][3] - mean) * rstd * gg[3] + eb[3];
      *(float4*)&hout[(size_t)(r0 + rr + a) * Hd + cc] = o;
    }
  }
}

// ---------------- readout: softplus(silu([h,x]@Wr1+b)@Wr2+b) ----------------
__global__ __launch_bounds__(256) void k_out(const float* __restrict__ x,
    const float* __restrict__ hin, const float* __restrict__ Wr1,
    const float* __restrict__ br1, const float* __restrict__ Wr2,
    const float* __restrict__ br2, float* __restrict__ out) {
  __shared__ float rT[Hd + Fd][US];  // 192 x 36 (27 KB)
  const int t = threadIdx.x;
  const int r0 = blockIdx.x * RB;
  {
    const int r = t >> 3, s = t & 7;
    const int i = r0 + r;
    const float* hr = hin + (size_t)i * Hd + (s << 4);
#pragma unroll
    for (int u = 0; u < 4; ++u) {
      float4 v = *(const float4*)(hr + (u << 2));
      const int c = (s << 4) + (u << 2);
      rT[c + 0][r] = v.x; rT[c + 1][r] = v.y;
      rT[c + 2][r] = v.z; rT[c + 3][r] = v.w;
    }
    const float* xr = x + (size_t)i * Fd + (s << 3);
    float4 x0 = *(const float4*)(xr);
    float4 x1 = *(const float4*)(xr + 4);
    const int c = Hd + (s << 3);
    rT[c + 0][r] = x0.x; rT[c + 1][r] = x0.y;
    rT[c + 2][r] = x0.z; rT[c + 3][r] = x0.w;
    rT[c + 4][r] = x1.x; rT[c + 5][r] = x1.y;
    rT[c + 6][r] = x1.z; rT[c + 7][r] = x1.w;
  }
  __syncthreads();
  const int rg = t >> 5, cg = t & 31;
  const int rr = rg << 2, cc = cg << 2;
  float acc[4][4] = {};
#pragma unroll 4
  for (int k = 0; k < Hd + Fd; ++k) {
    float4 uv = *(const float4*)&rT[k][rr];
    float4 wv = *(const float4*)&Wr1[k * Hd + cc];
    FMA16(acc, uv, wv)
  }
  float4 b1 = *(const float4*)&br1[cc];
  float bb1[4] = {b1.x, b1.y, b1.z, b1.w};
  float4 w2 = *(const float4*)&Wr2[cc];
  float ww[4] = {w2.x, w2.y, w2.z, w2.w};
  float part[4];
#pragma unroll
  for (int a = 0; a < 4; ++a) {
    part[a] = 0.f;
#pragma unroll
    for (int b = 0; b < 4; ++b) {
      const float z = acc[a][b] + bb1[b];
      const float sil = z / (1.0f + __expf(-z));
      part[a] = fmaf(sil, ww[b], part[a]);
    }
  }
#pragma unroll
  for (int m = 1; m < 32; m <<= 1) {
#pragma unroll
    for (int a = 0; a < 4; ++a) part[a] += __shfl_xor(part[a], m);
  }
  if (cg == 0) {
    const float bias = br2[0];
#pragma unroll
    for (int a = 0; a < 4; ++a) {
      const float rv = part[a] + bias;
      out[r0 + rr + a] = fmaxf(rv, 0.0f) + log1pf(__expf(-fabsf(rv)));
    }
  }
}

extern "C" void kernel_launch(void* const* d_in, const int* in_sizes, int n_in,
                              void* d_out, int out_size, void* d_ws, size_t ws_size,
                              hipStream_t stream) {
  const float* x    = (const float*)d_in[0];
  const float* W_in = (const float*)d_in[1];
  const float* b_in = (const float*)d_in[2];
  const float* W_m1 = (const float*)d_in[3];
  const float* b_m1 = (const float*)d_in[4];
  const float* W_m2 = (const float*)d_in[5];
  const float* b_m2 = (const float*)d_in[6];
  const float* ln_g = (const float*)d_in[7];
  const float* ln_b = (const float*)d_in[8];
  const float* W_r1 = (const float*)d_in[9];
  const float* b_r1 = (const float*)d_in[10];
  const float* W_r2 = (const float*)d_in[11];
  const float* b_r2 = (const float*)d_in[12];
  float* out = (float*)d_out;

  char* ws = (char*)d_ws;
  const size_t MB = (size_t)1 << 20;
  float*          hidA = (float*)(ws);                 // 8 MB
  float*          hidB = (float*)(ws + 8 * MB);        // 8 MB (aliases partbuf)
  unsigned*       partb = (unsigned*)(ws + 8 * MB);    // 4 MB, dead before hidB use
  short*          xbhi = (short*)(ws + 16 * MB);       // 2 MB
  short*          xblo = (short*)(ws + 18 * MB);       // 2 MB
  unsigned short* nidx = (unsigned short*)(ws + 20 * MB);  // 1 MB
  float*          nw   = (float*)(ws + 21 * MB);       // 2 MB
  float*          sq   = (float*)(ws + 23 * MB);       // 64 KB

  k_input<<<dim3(Nn / 2), dim3(256), 0, stream>>>(x, W_in, b_in, hidA, sq);
  k_prep<<<dim3(Nn * 8 / 256), dim3(256), 0, stream>>>(x, xbhi, xblo);
  k_knn<<<dim3(Nn / 32 * 2), dim3(256), 0, stream>>>(xbhi, xblo, sq, partb);
  k_merge<<<dim3(Nn / 4), dim3(256), 0, stream>>>(partb, nidx, nw);
  k_step<<<dim3(Nn / RB), dim3(256), 0, stream>>>(x, hidA, nidx, nw, W_m1, b_m1,
                                                  W_m2, b_m2, ln_g, ln_b, hidB);
  k_step<<<dim3(Nn / RB), dim3(256), 0, stream>>>(x, hidB, nidx, nw, W_m1, b_m1,
                                                  W_m2, b_m2, ln_g, ln_b, hidA);
  k_out<<<dim3(Nn / RB), dim3(256), 0, stream>>>(x, hidA, W_r1, b_r1, W_r2, b_r2, out);
}